// Round 1
// baseline (748.200 us; speedup 1.0000x reference)
//
#include <hip/hip_runtime.h>

// Trajectron sliding-window LSTM embed:
//   inputs [T=256, B=128, N=4, D=2] f32
//   his LSTM: H=32 over inputs[:, :, 3, :], int LSTM: H=8 over inputs[:, :, 0, :]
//   window length 64 ending at t (fresh state at first valid step)
//   out[t,b,:] = [h_his | h_int] @ W_out.T + b_out   -> [256,128,2] f32

static __device__ __forceinline__ float fsig(float x) {
    return 1.0f / (1.0f + __expf(-x));
}
static __device__ __forceinline__ float ftanh_fast(float x) {
    x = fminf(15.0f, fmaxf(-15.0f, x));   // avoid inf/inf NaN for |c| large
    const float e = __expf(-2.0f * x);
    return (1.0f - e) / (1.0f + e);
}

// Block: 320 threads = 4 waves "his" (8 chains x 32 lanes) + 1 wave "int"
// (8 chains x 8 lanes). All 8 chains of a block share the same t, so the
// step-loop trip count is block-uniform and __syncthreads is legal.
__global__ __launch_bounds__(320) void traj_lstm_kernel(
    const float* __restrict__ inp,       // [256][128][4][2]
    const float* __restrict__ Wih_his,   // [128][2]
    const float* __restrict__ Whh_his,   // [128][32]
    const float* __restrict__ bih_his,   // [128]
    const float* __restrict__ bhh_his,   // [128]
    const float* __restrict__ Wih_int,   // [32][2]
    const float* __restrict__ Whh_int,   // [32][8]
    const float* __restrict__ bih_int,   // [32]
    const float* __restrict__ bhh_int,   // [32]
    const float* __restrict__ W_out,     // [2][40]
    const float* __restrict__ b_out,     // [2]
    float* __restrict__ out)             // [256][128][2]
{
    __shared__ float4 hb[2][8][8];   // his h broadcast: [buf][group][k/4]
    __shared__ float4 ib[2][8][2];   // int h broadcast: [buf][group][k/4]
    __shared__ float  ipart[8][2];   // int partial projection per chain

    const int tid    = threadIdx.x;
    const int chain0 = blockIdx.x * 8;
    const int t      = chain0 >> 7;                    // uniform per block
    const int s0     = (t >= 63) ? 0 : (63 - t);
    const int nsteps = 64 - s0;                        // min(t+1, 64)
    const int tau0   = (t >= 63) ? (t - 63) : 0;

    if (tid < 256) {
        // ---------------- HIS LSTM: H=32, lane j owns hidden unit j -------
        const int g = tid >> 5, j = tid & 31;
        const int chain = chain0 + g;
        const int b = chain & 127;

        // Whh rows {j, 32+j, 64+j, 96+j} -> 128 floats in VGPRs
        float4 w[4][8];
        float bias[4], wx0[4], wx1[4];
#pragma unroll
        for (int gi = 0; gi < 4; ++gi) {
            const int r = gi * 32 + j;
            const float4* row = reinterpret_cast<const float4*>(Whh_his + r * 32);
#pragma unroll
            for (int kk = 0; kk < 8; ++kk) w[gi][kk] = row[kk];
            bias[gi] = bih_his[r] + bhh_his[r];
            wx0[gi]  = Wih_his[r * 2 + 0];
            wx1[gi]  = Wih_his[r * 2 + 1];
        }

        float h = 0.0f, c = 0.0f;
        reinterpret_cast<float*>(&hb[0][g][0])[j] = 0.0f;
        __syncthreads();

        const float* xp = inp + ((tau0 * 128 + b) * 4 + 3) * 2;  // n = 3
        const float4* rbuf = &hb[0][g][0];
        float4*       wbuf = &hb[1][g][0];

        for (int s = 0; s < nsteps; ++s) {
            const float x0 = xp[0], x1 = xp[1];
            xp += 1024;   // next tau: B*N*D = 128*4*2 floats

            float a0 = fmaf(wx1[0], x1, fmaf(wx0[0], x0, bias[0]));
            float a1 = fmaf(wx1[1], x1, fmaf(wx0[1], x0, bias[1]));
            float a2 = fmaf(wx1[2], x1, fmaf(wx0[2], x0, bias[2]));
            float a3 = fmaf(wx1[3], x1, fmaf(wx0[3], x0, bias[3]));

#pragma unroll
            for (int kk = 0; kk < 8; ++kk) {
                const float4 hv = rbuf[kk];
                const float4 w0 = w[0][kk], w1 = w[1][kk];
                const float4 w2 = w[2][kk], w3 = w[3][kk];
                a0 = fmaf(w0.x, hv.x, a0); a0 = fmaf(w0.y, hv.y, a0);
                a0 = fmaf(w0.z, hv.z, a0); a0 = fmaf(w0.w, hv.w, a0);
                a1 = fmaf(w1.x, hv.x, a1); a1 = fmaf(w1.y, hv.y, a1);
                a1 = fmaf(w1.z, hv.z, a1); a1 = fmaf(w1.w, hv.w, a1);
                a2 = fmaf(w2.x, hv.x, a2); a2 = fmaf(w2.y, hv.y, a2);
                a2 = fmaf(w2.z, hv.z, a2); a2 = fmaf(w2.w, hv.w, a2);
                a3 = fmaf(w3.x, hv.x, a3); a3 = fmaf(w3.y, hv.y, a3);
                a3 = fmaf(w3.z, hv.z, a3); a3 = fmaf(w3.w, hv.w, a3);
            }

            const float ig = fsig(a0), fg = fsig(a1);
            const float gg = ftanh_fast(a2), og = fsig(a3);
            c = fmaf(fg, c, ig * gg);
            h = og * ftanh_fast(c);

            reinterpret_cast<float*>(wbuf)[j] = h;
            __syncthreads();
            const float4* tmp = rbuf; rbuf = wbuf; wbuf = const_cast<float4*>(tmp);
        }

        // projection partials: out_c += W_out[c][j] * h, reduce over 32 lanes
        float p0 = W_out[j]      * h;
        float p1 = W_out[40 + j] * h;
#pragma unroll
        for (int m = 16; m >= 1; m >>= 1) {
            p0 += __shfl_xor(p0, m, 32);
            p1 += __shfl_xor(p1, m, 32);
        }
        __syncthreads();   // pairs with int wave's final barrier (ipart ready)
        if (j == 0) {
            float2 o;
            o.x = p0 + ipart[g][0] + b_out[0];
            o.y = p1 + ipart[g][1] + b_out[1];
            reinterpret_cast<float2*>(out)[chain] = o;
        }
    } else {
        // ---------------- INT LSTM: H=8, lane j owns hidden unit j --------
        const int tid2 = tid - 256;
        const int g = tid2 >> 3, j = tid2 & 7;
        const int chain = chain0 + g;
        const int b = chain & 127;

        float4 w[4][2];
        float bias[4], wx0[4], wx1[4];
#pragma unroll
        for (int gi = 0; gi < 4; ++gi) {
            const int r = gi * 8 + j;
            const float4* row = reinterpret_cast<const float4*>(Whh_int + r * 8);
            w[gi][0] = row[0];
            w[gi][1] = row[1];
            bias[gi] = bih_int[r] + bhh_int[r];
            wx0[gi]  = Wih_int[r * 2 + 0];
            wx1[gi]  = Wih_int[r * 2 + 1];
        }

        float h = 0.0f, c = 0.0f;
        reinterpret_cast<float*>(&ib[0][g][0])[j] = 0.0f;
        __syncthreads();

        const float* xp = inp + ((tau0 * 128 + b) * 4 + 0) * 2;  // n = 0
        const float4* rbuf = &ib[0][g][0];
        float4*       wbuf = &ib[1][g][0];

        for (int s = 0; s < nsteps; ++s) {
            const float x0 = xp[0], x1 = xp[1];
            xp += 1024;

            float a0 = fmaf(wx1[0], x1, fmaf(wx0[0], x0, bias[0]));
            float a1 = fmaf(wx1[1], x1, fmaf(wx0[1], x0, bias[1]));
            float a2 = fmaf(wx1[2], x1, fmaf(wx0[2], x0, bias[2]));
            float a3 = fmaf(wx1[3], x1, fmaf(wx0[3], x0, bias[3]));

#pragma unroll
            for (int kk = 0; kk < 2; ++kk) {
                const float4 hv = rbuf[kk];
                const float4 w0 = w[0][kk], w1 = w[1][kk];
                const float4 w2 = w[2][kk], w3 = w[3][kk];
                a0 = fmaf(w0.x, hv.x, a0); a0 = fmaf(w0.y, hv.y, a0);
                a0 = fmaf(w0.z, hv.z, a0); a0 = fmaf(w0.w, hv.w, a0);
                a1 = fmaf(w1.x, hv.x, a1); a1 = fmaf(w1.y, hv.y, a1);
                a1 = fmaf(w1.z, hv.z, a1); a1 = fmaf(w1.w, hv.w, a1);
                a2 = fmaf(w2.x, hv.x, a2); a2 = fmaf(w2.y, hv.y, a2);
                a2 = fmaf(w2.z, hv.z, a2); a2 = fmaf(w2.w, hv.w, a2);
                a3 = fmaf(w3.x, hv.x, a3); a3 = fmaf(w3.y, hv.y, a3);
                a3 = fmaf(w3.z, hv.z, a3); a3 = fmaf(w3.w, hv.w, a3);
            }

            const float ig = fsig(a0), fg = fsig(a1);
            const float gg = ftanh_fast(a2), og = fsig(a3);
            c = fmaf(fg, c, ig * gg);
            h = og * ftanh_fast(c);

            reinterpret_cast<float*>(wbuf)[j] = h;
            __syncthreads();
            const float4* tmp = rbuf; rbuf = wbuf; wbuf = const_cast<float4*>(tmp);
        }

        float p0 = W_out[32 + j]      * h;   // emb index 32 + j
        float p1 = W_out[40 + 32 + j] * h;
#pragma unroll
        for (int m = 4; m >= 1; m >>= 1) {
            p0 += __shfl_xor(p0, m, 8);
            p1 += __shfl_xor(p1, m, 8);
        }
        if (j == 0) { ipart[g][0] = p0; ipart[g][1] = p1; }
        __syncthreads();   // publish ipart to his lanes
    }
}

extern "C" void kernel_launch(void* const* d_in, const int* in_sizes, int n_in,
                              void* d_out, int out_size, void* d_ws, size_t ws_size,
                              hipStream_t stream) {
    const float* inp     = (const float*)d_in[0];
    const float* Wih_his = (const float*)d_in[1];
    const float* Whh_his = (const float*)d_in[2];
    const float* bih_his = (const float*)d_in[3];
    const float* bhh_his = (const float*)d_in[4];
    const float* Wih_int = (const float*)d_in[5];
    const float* Whh_int = (const float*)d_in[6];
    const float* bih_int = (const float*)d_in[7];
    const float* bhh_int = (const float*)d_in[8];
    const float* W_out   = (const float*)d_in[9];
    const float* b_out   = (const float*)d_in[10];
    float* out = (float*)d_out;

    // 4096 blocks x 320 threads: 8 chains per block (32768 chains total)
    traj_lstm_kernel<<<dim3(4096), dim3(320), 0, stream>>>(
        inp, Wih_his, Whh_his, bih_his, bhh_his,
        Wih_int, Whh_int, bih_int, bhh_int, W_out, b_out, out);
}

// Round 2
// 534.137 us; speedup vs baseline: 1.4008x; 1.4008x over previous
//
#include <hip/hip_runtime.h>

// Trajectron sliding-window LSTM embed:
//   inputs [T=256, B=128, N=4, D=2] f32
//   his LSTM H=32 over n=3; int LSTM H=8 over n=0; window 64 ending at t
//   out[t,b,:] = [h_his | h_int] @ W_out.T + b_out   -> [256,128,2] f32
//
// Round-2 structure: one wave64 per his chain (32 units x 2 gate-pairs/lane),
// intra-wave LDS broadcast of h (NO __syncthreads in the step loop), packed
// float2 k-dim -> v_pk_fma_f32, gate-pair specialization to halve
// transcendentals. Single block barrier at the end to combine int partials.

typedef float v2f __attribute__((ext_vector_type(2)));

static __device__ __forceinline__ float fast_exp2(float x) {
#if __has_builtin(__builtin_amdgcn_exp2f)
    return __builtin_amdgcn_exp2f(x);
#else
    return exp2f(x);
#endif
}
static __device__ __forceinline__ float fast_rcp(float x) {
#if __has_builtin(__builtin_amdgcn_rcpf)
    return __builtin_amdgcn_rcpf(x);
#else
    return 1.0f / x;
#endif
}
// sigmoid(x) = 1/(1+2^(-x*log2e)); saturates to 0/1 cleanly (inf -> rcp -> 0)
static __device__ __forceinline__ float fast_sig(float x) {
    return fast_rcp(1.0f + fast_exp2(-1.44269504f * x));
}
// tanh(x) = 1 - 2/(1+2^(2x*log2e)); saturates to +/-1 cleanly, no clamps
static __device__ __forceinline__ float fast_tanh(float x) {
    return fmaf(-2.0f, fast_rcp(1.0f + fast_exp2(2.88539008f * x)), 1.0f);
}

// Intra-wave LDS publish fence: no s_barrier. Wave is lockstep; we only need
// (a) compiler to not reorder LDS ops across this point, (b) lgkmcnt drained.
static __device__ __forceinline__ void lds_fence_wave() {
    __builtin_amdgcn_wave_barrier();
    asm volatile("s_waitcnt lgkmcnt(0)" ::: "memory");
    __builtin_amdgcn_wave_barrier();
}

// One LSTM chain on 2H contiguous lanes (lane in [0, 2H)).
//   lane = p*H + j : p=0 owns gates (i,f) of unit j; p=1 owns (g,o).
//   Per step: read full h[H] from LDS (broadcast), 2 gate dot-products packed
//   over k, activation (1 sig-like per gate via sig/tanh relation), exchange
//   partner gates via shfl_xor(H), p=0 lanes update c,h and publish h.
// Returns final h (valid on p==0 lanes; 0 on p==1 lanes).
template <int H>
static __device__ __forceinline__ float lstm_chain(
    const float* __restrict__ xp,   // &inp[tau0][b][n][0], step stride 1024
    const float* __restrict__ Wih,  // [4H][2]
    const float* __restrict__ Whh,  // [4H][H]
    const float* __restrict__ bih,  // [4H]
    const float* __restrict__ bhh,  // [4H]
    float* lds,                     // per-chain H-float buffer (x2 at +dboff)
    int dboff, int nsteps, int lane)
{
    constexpr int K2 = H / 2;   // float2 packs per gate row
    constexpr int K4 = H / 4;   // float4 reads of h
    const int j = lane % H;
    const int p = (lane / H) & 1;

    const int rA = p * 2 * H + j;   // p0: i-row j   | p1: g-row j
    const int rB = rA + H;          // p0: f-row j   | p1: o-row j

    // Two Whh rows (2*H floats) resident in VGPRs, packed over k.
    v2f wA[K2], wB[K2];
    {
        const v2f* a2 = reinterpret_cast<const v2f*>(Whh + rA * H);
        const v2f* b2 = reinterpret_cast<const v2f*>(Whh + rB * H);
#pragma unroll
        for (int m = 0; m < K2; ++m) { wA[m] = a2[m]; wB[m] = b2[m]; }
    }
    const float biasA = bih[rA] + bhh[rA];
    const float biasB = bih[rB] + bhh[rB];
    const float wxA0 = Wih[rA * 2 + 0], wxA1 = Wih[rA * 2 + 1];
    const float wxB0 = Wih[rB * 2 + 0], wxB1 = Wih[rB * 2 + 1];

    // vA = p ? tanh(aA) : sig(aA), via tanh(x) = 2*sig(2x)-1:
    //   vA = fmaf(sclA, sig(sclA*aA), offA)
    const float sclA = p ? 2.0f : 1.0f;
    const float offA = p ? -1.0f : 0.0f;

    if (p == 0) lds[j] = 0.0f;      // h init, published via first loop fence

    float c = 0.0f, h = 0.0f;
    float* cur = lds;
    float* nxt = lds + dboff;

    for (int s = 0; s < nsteps; ++s) {
        lds_fence_wave();           // drain prev publish + prev reads (WAR)

        const float x0 = xp[0], x1 = xp[1];
        xp += 1024;                 // B*N*D = 128*4*2

        v2f accA = {0.0f, 0.0f}, accB = {0.0f, 0.0f};
        const float4* h4 = reinterpret_cast<const float4*>(cur);
#pragma unroll
        for (int q = 0; q < K4; ++q) {
            const float4 hv = h4[q];            // broadcast read: no conflicts
            const v2f h01 = {hv.x, hv.y};
            const v2f h23 = {hv.z, hv.w};
            accA += wA[2 * q] * h01;            // -> v_pk_fma_f32
            accA += wA[2 * q + 1] * h23;
            accB += wB[2 * q] * h01;
            accB += wB[2 * q + 1] * h23;
        }
        const float aA = fmaf(wxA1, x1, fmaf(wxA0, x0, biasA)) + (accA.x + accA.y);
        const float aB = fmaf(wxB1, x1, fmaf(wxB0, x0, biasB)) + (accB.x + accB.y);

        const float sA = fast_sig(sclA * aA);
        const float vA = fmaf(sclA, sA, offA);  // p0: sig(i) | p1: tanh(g)
        const float vB = fast_sig(aB);          // p0: sig(f) | p1: sig(o)

        const float oA = __shfl_xor(vA, H);     // partner's A-gate
        const float oB = __shfl_xor(vB, H);     // partner's B-gate

        if (p == 0) {
            // s_i=vA  s_f=vB  t_g=oA  s_o=oB
            c = fmaf(vB, c, vA * oA);
            h = oB * fast_tanh(c);
            nxt[j] = h;                          // publish for next step
        }
        float* tmp = cur; cur = nxt; nxt = tmp;
    }
    return h;
}

// Block: 320 threads = 4 his waves (1 chain each) + 1 int wave (4 chains x 16
// lanes). Step loops are barrier-free; ONE __syncthreads at the end combines.
__global__ __launch_bounds__(320, 3) void traj_lstm_kernel(
    const float* __restrict__ inp,       // [256][128][4][2]
    const float* __restrict__ Wih_his,   // [128][2]
    const float* __restrict__ Whh_his,   // [128][32]
    const float* __restrict__ bih_his,   // [128]
    const float* __restrict__ bhh_his,   // [128]
    const float* __restrict__ Wih_int,   // [32][2]
    const float* __restrict__ Whh_int,   // [32][8]
    const float* __restrict__ bih_int,   // [32]
    const float* __restrict__ bhh_int,   // [32]
    const float* __restrict__ W_out,     // [2][40]
    const float* __restrict__ b_out,     // [2]
    float* __restrict__ out)             // [256][128][2]
{
    __shared__ float hls[2][4][32];   // his h, double-buffered, per chain
    __shared__ float ils[2][4][8];    // int h
    __shared__ float ipart[4][2];     // int projection partials per chain

    const int tid  = threadIdx.x;
    const int wave = tid >> 6;
    const int lane = tid & 63;

    const int chain0 = blockIdx.x * 4;
    const int t      = chain0 >> 7;                 // uniform per block
    const int nsteps = (t >= 63) ? 64 : (t + 1);
    const int tau0   = (t >= 63) ? (t - 63) : 0;

    float q0 = 0.0f, q1 = 0.0f;
    int myChain = -1;

    if (wave < 4) {
        // ---------------- HIS chain: H=32, one wave ----------------------
        const int chain = chain0 + wave;
        const int b = chain & 127;
        myChain = chain;
        const float* xp = inp + ((tau0 * 128 + b) * 8 + 6);   // n=3
        const float h = lstm_chain<32>(xp, Wih_his, Whh_his, bih_his, bhh_his,
                                       &hls[0][wave][0], 4 * 32, nsteps, lane);
        // projection partials (h==0 on p1 lanes; reduce within 32-lane half)
        const int j = lane & 31;
        q0 = W_out[j] * h;
        q1 = W_out[40 + j] * h;
#pragma unroll
        for (int m = 16; m >= 1; m >>= 1) {
            q0 += __shfl_xor(q0, m);
            q1 += __shfl_xor(q1, m);
        }
    } else {
        // ---------------- INT chains: H=8, 4 chains x 16 lanes -----------
        const int cg = lane >> 4;          // chain within block
        const int l16 = lane & 15;
        const int chain = chain0 + cg;
        const int b = chain & 127;
        const float* xp = inp + ((tau0 * 128 + b) * 8 + 0);   // n=0
        const float h = lstm_chain<8>(xp, Wih_int, Whh_int, bih_int, bhh_int,
                                      &ils[0][cg][0], 4 * 8, nsteps, l16);
        const int j = l16 & 7;
        float r0 = W_out[32 + j] * h;          // emb index 32+j
        float r1 = W_out[40 + 32 + j] * h;
#pragma unroll
        for (int m = 4; m >= 1; m >>= 1) {
            r0 += __shfl_xor(r0, m);
            r1 += __shfl_xor(r1, m);
        }
        if (l16 == 0) { ipart[cg][0] = r0; ipart[cg][1] = r1; }
    }

    __syncthreads();   // publish ipart across waves (only block-wide sync)

    if (wave < 4 && lane == 0) {
        float2 o;
        o.x = q0 + ipart[wave][0] + b_out[0];
        o.y = q1 + ipart[wave][1] + b_out[1];
        reinterpret_cast<float2*>(out)[myChain] = o;
    }
}

extern "C" void kernel_launch(void* const* d_in, const int* in_sizes, int n_in,
                              void* d_out, int out_size, void* d_ws, size_t ws_size,
                              hipStream_t stream) {
    const float* inp     = (const float*)d_in[0];
    const float* Wih_his = (const float*)d_in[1];
    const float* Whh_his = (const float*)d_in[2];
    const float* bih_his = (const float*)d_in[3];
    const float* bhh_his = (const float*)d_in[4];
    const float* Wih_int = (const float*)d_in[5];
    const float* Whh_int = (const float*)d_in[6];
    const float* bih_int = (const float*)d_in[7];
    const float* bhh_int = (const float*)d_in[8];
    const float* W_out   = (const float*)d_in[9];
    const float* b_out   = (const float*)d_in[10];
    float* out = (float*)d_out;

    // 8192 blocks x 320 threads: 4 chains per block (32768 chains total)
    traj_lstm_kernel<<<dim3(8192), dim3(320), 0, stream>>>(
        inp, Wih_his, Whh_his, bih_his, bhh_his,
        Wih_int, Whh_int, bih_int, bhh_int, W_out, b_out, out);
}

// Round 3
// 477.674 us; speedup vs baseline: 1.5663x; 1.1182x over previous
//
#include <hip/hip_runtime.h>

// Trajectron sliding-window LSTM embed:
//   inputs [T=256, B=128, N=4, D=2] f32
//   his LSTM H=32 over n=3; int LSTM H=8 over n=0; window 64 ending at t
//   out[t,b,:] = [h_his | h_int] @ W_out.T + b_out   -> [256,128,2] f32
//
// Round-3: NO LDS in the step loop. h broadcast via v_readlane -> SGPR pairs
// -> v_pk_fma_f32 (his), per-lane-index __shfl/ds_bpermute (int). Weights
// pinned in VGPRs with an empty-asm opacity barrier (round-2 showed the
// allocator remats the loads otherwise: VGPR_Count=52 < 64 weight floats).
// Round-2's 8x ds_read_b128/lane-step was 8KB LDS-pipe traffic per
// chain-step (~213us at the 69TB/s LDS ceiling) -- that was the bottleneck.

typedef float v2f __attribute__((ext_vector_type(2)));

static __device__ __forceinline__ float fast_exp2(float x) {
#if __has_builtin(__builtin_amdgcn_exp2f)
    return __builtin_amdgcn_exp2f(x);
#else
    return exp2f(x);
#endif
}
static __device__ __forceinline__ float fast_rcp(float x) {
#if __has_builtin(__builtin_amdgcn_rcpf)
    return __builtin_amdgcn_rcpf(x);
#else
    return 1.0f / x;
#endif
}
// sigmoid(x) = 1/(1+2^(-x*log2e)); saturates cleanly to 0/1
static __device__ __forceinline__ float fast_sig(float x) {
    return fast_rcp(1.0f + fast_exp2(-1.44269504f * x));
}
// tanh(x) = 1 - 2/(1+2^(2x*log2e)); saturates cleanly to +/-1
static __device__ __forceinline__ float fast_tanh(float x) {
    return fmaf(-2.0f, fast_rcp(1.0f + fast_exp2(2.88539008f * x)), 1.0f);
}
// wave-uniform broadcast of lane l's value (ignores exec; l must be uniform)
static __device__ __forceinline__ float lane_bcast(float v, int l) {
    return __uint_as_float(__builtin_amdgcn_readlane(__float_as_uint(v), l));
}

// Block: 320 threads = 4 his waves (1 chain each: 32 units x 2 gate-pairs)
// + 1 int wave (4 chains x 16 lanes). No barriers except the final combine.
__global__ __launch_bounds__(320, 3) void traj_lstm_kernel(
    const float* __restrict__ inp,       // [256][128][4][2]
    const float* __restrict__ Wih_his,   // [128][2]
    const float* __restrict__ Whh_his,   // [128][32]
    const float* __restrict__ bih_his,   // [128]
    const float* __restrict__ bhh_his,   // [128]
    const float* __restrict__ Wih_int,   // [32][2]
    const float* __restrict__ Whh_int,   // [32][8]
    const float* __restrict__ bih_int,   // [32]
    const float* __restrict__ bhh_int,   // [32]
    const float* __restrict__ W_out,     // [2][40]
    const float* __restrict__ b_out,     // [2]
    float* __restrict__ out)             // [256][128][2]
{
    __shared__ float ipart[4][2];     // int projection partials per chain

    const int tid  = threadIdx.x;
    const int wave = tid >> 6;
    const int lane = tid & 63;

    const int chain0 = blockIdx.x * 4;
    const int t      = chain0 >> 7;                 // uniform per block
    const int nsteps = (t >= 63) ? 64 : (t + 1);
    const int tau0   = (t >= 63) ? (t - 63) : 0;

    if (wave < 4) {
        // ---------------- HIS chain: H=32, one wave ----------------------
        // lane = p*32 + j : p=0 owns gates (i,f) of unit j; p=1 owns (g,o).
        const int chain = __builtin_amdgcn_readfirstlane(chain0 + wave);
        const int b = chain & 127;
        const int j = lane & 31;
        const int p = lane >> 5;

        const int rA = p * 64 + j;    // p0: i-row j | p1: g-row j
        const int rB = rA + 32;       // p0: f-row j | p1: o-row j

        // 2 Whh rows (64 floats) pinned in VGPRs, packed over k.
        v2f wA[16], wB[16];
        {
            const v2f* a2 = reinterpret_cast<const v2f*>(Whh_his + rA * 32);
            const v2f* b2 = reinterpret_cast<const v2f*>(Whh_his + rB * 32);
#pragma unroll
            for (int m = 0; m < 16; ++m) {
                wA[m] = a2[m];
                wB[m] = b2[m];
                asm volatile("" : "+v"(wA[m]), "+v"(wB[m]));  // no remat
            }
        }
        const float biasA = bih_his[rA] + bhh_his[rA];
        const float biasB = bih_his[rB] + bhh_his[rB];
        const float wxA0 = Wih_his[rA * 2], wxA1 = Wih_his[rA * 2 + 1];
        const float wxB0 = Wih_his[rB * 2], wxB1 = Wih_his[rB * 2 + 1];

        // vA = p ? tanh(aA) : sig(aA)  via tanh(x)=2*sig(2x)-1
        const float sclA = p ? 2.0f : 1.0f;
        const float offA = p ? -1.0f : 0.0f;

        // wave-uniform x address -> scalar-load path
        const float* xs = inp + __builtin_amdgcn_readfirstlane(
                                    tau0 * 1024 + b * 8 + 6);   // n=3

        float c = 0.0f, h = 0.0f;
        for (int s = 0; s < nsteps; ++s) {
            const float x0 = xs[0], x1 = xs[1];
            xs += 1024;                           // B*N*D

            v2f aA0 = {0.f, 0.f}, aA1 = {0.f, 0.f};
            v2f aB0 = {0.f, 0.f}, aB1 = {0.f, 0.f};
#pragma unroll
            for (int m = 0; m < 16; m += 2) {
                v2f hp0, hp1;                     // h via SGPR broadcast
                hp0.x = lane_bcast(h, 2 * m);
                hp0.y = lane_bcast(h, 2 * m + 1);
                hp1.x = lane_bcast(h, 2 * m + 2);
                hp1.y = lane_bcast(h, 2 * m + 3);
                aA0 += wA[m] * hp0;               // v_pk_fma_f32
                aB0 += wB[m] * hp0;
                aA1 += wA[m + 1] * hp1;
                aB1 += wB[m + 1] * hp1;
            }
            const v2f aAv = aA0 + aA1;
            const v2f aBv = aB0 + aB1;
            const float aA = fmaf(wxA1, x1, fmaf(wxA0, x0, biasA)) + (aAv.x + aAv.y);
            const float aB = fmaf(wxB1, x1, fmaf(wxB0, x0, biasB)) + (aBv.x + aBv.y);

            const float sA = fast_sig(sclA * aA);
            const float vA = fmaf(sclA, sA, offA);  // p0: sig(i) | p1: tanh(g)
            const float vB = fast_sig(aB);          // p0: sig(f) | p1: sig(o)
            const float oA = __shfl_xor(vA, 32);
            const float oB = __shfl_xor(vB, 32);

            const float gi = p ? oA : vA;           // branchless: all lanes
            const float gf = p ? oB : vB;           // hold valid c,h
            const float gg = p ? vA : oA;
            const float go = p ? vB : oB;
            c = fmaf(gf, c, gi * gg);
            h = go * fast_tanh(c);
        }

        // projection partials; halves are identical, reduce within 32 lanes
        float q0 = W_out[j] * h;
        float q1 = W_out[40 + j] * h;
#pragma unroll
        for (int m = 16; m >= 1; m >>= 1) {
            q0 += __shfl_xor(q0, m);
            q1 += __shfl_xor(q1, m);
        }
        __syncthreads();   // ipart ready (int wave reached its store)
        if (lane == 0) {
            float2 o;
            o.x = q0 + ipart[wave][0] + b_out[0];
            o.y = q1 + ipart[wave][1] + b_out[1];
            reinterpret_cast<float2*>(out)[chain] = o;
        }
    } else {
        // ---------------- INT chains: H=8, 4 chains x 16 lanes -----------
        const int g2  = lane >> 4;      // chain within block
        const int l16 = lane & 15;
        const int j   = l16 & 7;
        const int p   = l16 >> 3;
        const int chain = chain0 + g2;
        const int b = chain & 127;
        const int base = lane & 48;     // group base lane for h broadcast

        const int rA = p * 16 + j;
        const int rB = rA + 8;

        v2f wA[4], wB[4];
        {
            const v2f* a2 = reinterpret_cast<const v2f*>(Whh_int + rA * 8);
            const v2f* b2 = reinterpret_cast<const v2f*>(Whh_int + rB * 8);
#pragma unroll
            for (int m = 0; m < 4; ++m) {
                wA[m] = a2[m];
                wB[m] = b2[m];
                asm volatile("" : "+v"(wA[m]), "+v"(wB[m]));
            }
        }
        const float biasA = bih_int[rA] + bhh_int[rA];
        const float biasB = bih_int[rB] + bhh_int[rB];
        const float wxA0 = Wih_int[rA * 2], wxA1 = Wih_int[rA * 2 + 1];
        const float wxB0 = Wih_int[rB * 2], wxB1 = Wih_int[rB * 2 + 1];
        const float sclA = p ? 2.0f : 1.0f;
        const float offA = p ? -1.0f : 0.0f;

        const float* xs = inp + (tau0 * 1024 + b * 8 + 0);   // n=0

        float c = 0.0f, h = 0.0f;
        for (int s = 0; s < nsteps; ++s) {
            const float x0 = xs[0], x1 = xs[1];
            xs += 1024;

            v2f aAv = {0.f, 0.f}, aBv = {0.f, 0.f};
#pragma unroll
            for (int m = 0; m < 4; ++m) {
                v2f hp;                      // per-lane index -> ds_bpermute
                hp.x = __shfl(h, base + 2 * m);
                hp.y = __shfl(h, base + 2 * m + 1);
                aAv += wA[m] * hp;
                aBv += wB[m] * hp;
            }
            const float aA = fmaf(wxA1, x1, fmaf(wxA0, x0, biasA)) + (aAv.x + aAv.y);
            const float aB = fmaf(wxB1, x1, fmaf(wxB0, x0, biasB)) + (aBv.x + aBv.y);

            const float sA = fast_sig(sclA * aA);
            const float vA = fmaf(sclA, sA, offA);
            const float vB = fast_sig(aB);
            const float oA = __shfl_xor(vA, 8);
            const float oB = __shfl_xor(vB, 8);

            const float gi = p ? oA : vA;
            const float gf = p ? oB : vB;
            const float gg = p ? vA : oA;
            const float go = p ? vB : oB;
            c = fmaf(gf, c, gi * gg);
            h = go * fast_tanh(c);
        }

        float r0 = W_out[32 + j] * h;           // emb index 32+j
        float r1 = W_out[40 + 32 + j] * h;
#pragma unroll
        for (int m = 4; m >= 1; m >>= 1) {
            r0 += __shfl_xor(r0, m);
            r1 += __shfl_xor(r1, m);
        }
        if (l16 == 0) { ipart[g2][0] = r0; ipart[g2][1] = r1; }
        __syncthreads();   // publish ipart to his waves
    }
}

extern "C" void kernel_launch(void* const* d_in, const int* in_sizes, int n_in,
                              void* d_out, int out_size, void* d_ws, size_t ws_size,
                              hipStream_t stream) {
    const float* inp     = (const float*)d_in[0];
    const float* Wih_his = (const float*)d_in[1];
    const float* Whh_his = (const float*)d_in[2];
    const float* bih_his = (const float*)d_in[3];
    const float* bhh_his = (const float*)d_in[4];
    const float* Wih_int = (const float*)d_in[5];
    const float* Whh_int = (const float*)d_in[6];
    const float* bih_int = (const float*)d_in[7];
    const float* bhh_int = (const float*)d_in[8];
    const float* W_out   = (const float*)d_in[9];
    const float* b_out   = (const float*)d_in[10];
    float* out = (float*)d_out;

    // 8192 blocks x 320 threads: 4 chains per block (32768 chains total)
    traj_lstm_kernel<<<dim3(8192), dim3(320), 0, stream>>>(
        inp, Wih_his, Whh_his, bih_his, bhh_his,
        Wih_int, Whh_int, bih_int, bhh_int, W_out, b_out, out);
}